// Round 1
// baseline (261.748 us; speedup 1.0000x reference)
//
#include <hip/hip_runtime.h>

#define NUM_BINS 128
#define BATCH 128
#define HW (512 * 512)          // elements per image
#define BLOCKS_PER_IMG 32
#define ELEMS_PER_BLOCK (HW / BLOCKS_PER_IMG)   // 8192
#define HIST_THREADS 256
#define NUM_WAVES (HIST_THREADS / 64)

// ---------------------------------------------------------------------------
// Kernel 1: per-batch histogram with torch.histc(min=0,max=1) semantics.
// Per-wave replicated LDS histograms reduce LDS atomic contention; one
// global atomicAdd per (block, bin) at the end.
// ---------------------------------------------------------------------------
__global__ __launch_bounds__(HIST_THREADS) void hist_kernel(
    const float* __restrict__ x, unsigned int* __restrict__ hist) {
    __shared__ unsigned int lhist[NUM_WAVES][NUM_BINS];

    const int tid  = threadIdx.x;
    const int wave = tid >> 6;

    for (int i = tid; i < NUM_WAVES * NUM_BINS; i += HIST_THREADS)
        ((unsigned int*)lhist)[i] = 0u;
    __syncthreads();

    const int b   = blockIdx.x / BLOCKS_PER_IMG;
    const int blk = blockIdx.x % BLOCKS_PER_IMG;
    const float4* xp =
        (const float4*)(x + (size_t)b * HW + (size_t)blk * ELEMS_PER_BLOCK);
    const int n4 = ELEMS_PER_BLOCK / 4;   // 2048 float4 per block

    for (int i = tid; i < n4; i += HIST_THREADS) {
        float4 v = xp[i];
        float vals[4] = {v.x, v.y, v.z, v.w};
#pragma unroll
        for (int k = 0; k < 4; ++k) {
            float f = vals[k];
            if (f >= 0.0f && f <= 1.0f) {
                int idx = (int)floorf(f * (float)NUM_BINS);
                idx = min(idx, NUM_BINS - 1);   // f==1.0 -> last bin
                atomicAdd(&lhist[wave][idx], 1u);
            }
        }
    }
    __syncthreads();

    for (int i = tid; i < NUM_BINS; i += HIST_THREADS) {
        unsigned int s = 0u;
#pragma unroll
        for (int wv = 0; wv < NUM_WAVES; ++wv) s += lhist[wv][i];
        if (s) atomicAdd(&hist[b * NUM_BINS + i], s);
    }
}

// ---------------------------------------------------------------------------
// Kernel 2: tiny MLP  w[b] = (relu(hist[b] @ W1 + b1) @ W2 + b2)
// One wave per batch; lanes 0..15 each own one hidden unit.
// ---------------------------------------------------------------------------
__global__ __launch_bounds__(64) void mlp_kernel(
    const unsigned int* __restrict__ hist,
    const float* __restrict__ W1, const float* __restrict__ b1,
    const float* __restrict__ W2, const float* __restrict__ b2,
    float* __restrict__ w) {
    const int b = blockIdx.x;
    const int j = threadIdx.x;

    float h = 0.0f;
    if (j < 16) {
        float acc = b1[j];
        const unsigned int* hb = hist + b * NUM_BINS;
#pragma unroll 8
        for (int k = 0; k < NUM_BINS; ++k)
            acc = fmaf((float)hb[k], W1[k * 16 + j], acc);
        h = fmaxf(acc, 0.0f) * W2[j];   // W2 is [16,1]
    }
#pragma unroll
    for (int off = 32; off > 0; off >>= 1) h += __shfl_down(h, off);
    if (j == 0) w[b] = h + b2[0];
}

// ---------------------------------------------------------------------------
// Kernel 3: out = x * w[batch], vectorized float4 grid-stride.
// ---------------------------------------------------------------------------
__global__ __launch_bounds__(256) void scale_kernel(
    const float* __restrict__ x, const float* __restrict__ w,
    float* __restrict__ out) {
    const size_t total4 = (size_t)BATCH * HW / 4;   // 8,388,608
    const size_t stride = (size_t)gridDim.x * blockDim.x;
    for (size_t i = (size_t)blockIdx.x * blockDim.x + threadIdx.x; i < total4;
         i += stride) {
        int b = (int)(i >> 16);   // HW/4 = 65536 float4 per image
        float s = w[b];
        float4 v = ((const float4*)x)[i];
        v.x *= s; v.y *= s; v.z *= s; v.w *= s;
        ((float4*)out)[i] = v;
    }
}

extern "C" void kernel_launch(void* const* d_in, const int* in_sizes, int n_in,
                              void* d_out, int out_size, void* d_ws, size_t ws_size,
                              hipStream_t stream) {
    const float* x  = (const float*)d_in[0];
    const float* W1 = (const float*)d_in[1];
    const float* b1 = (const float*)d_in[2];
    const float* W2 = (const float*)d_in[3];
    const float* b2 = (const float*)d_in[4];
    float* out = (float*)d_out;

    unsigned int* hist = (unsigned int*)d_ws;                    // 128*128 u32 = 64 KiB
    float* w = (float*)((char*)d_ws + BATCH * NUM_BINS * sizeof(unsigned int));

    hipMemsetAsync(hist, 0, BATCH * NUM_BINS * sizeof(unsigned int), stream);

    hist_kernel<<<BATCH * BLOCKS_PER_IMG, HIST_THREADS, 0, stream>>>(x, hist);
    mlp_kernel<<<BATCH, 64, 0, stream>>>(hist, W1, b1, W2, b2, w);

    const int total4 = BATCH * HW / 4;
    int blocks = min((total4 + 255) / 256, 16384);
    scale_kernel<<<blocks, 256, 0, stream>>>(x, w, out);
}